// Round 1
// baseline (57.752 us; speedup 1.0000x reference)
//
#include <hip/hip_runtime.h>

#define B 32
#define S 2048
#define D 1280
#define R 50

// ---------------------------------------------------------------------------
// Pre-kernel: L[b] = sum(mask[b, :]).  One block per batch.
// ---------------------------------------------------------------------------
__global__ __launch_bounds__(256) void compute_len_kernel(
    const int* __restrict__ mask, int* __restrict__ Lbuf)
{
    const int b = blockIdx.x;
    const int t = threadIdx.x;
    const int* __restrict__ mrow = mask + (size_t)b * S;

    int sum = 0;
    for (int i = t; i < S; i += 256) sum += mrow[i];

    // wave (64-lane) shuffle reduction
    for (int off = 32; off > 0; off >>= 1) sum += __shfl_down(sum, off, 64);

    __shared__ int ws[4];
    const int wave = t >> 6;
    const int lane = t & 63;
    if (lane == 0) ws[wave] = sum;
    __syncthreads();
    if (t == 0) Lbuf[b] = ws[0] + ws[1] + ws[2] + ws[3];
}

// ---------------------------------------------------------------------------
// Main kernel: one block per (b, r) window.  320 threads; lane t owns float4
// column t (D = 1280 = 320 * 4).  Single pass: sum + sum-of-squares.
// ---------------------------------------------------------------------------
__global__ __launch_bounds__(320) void window_stats_kernel(
    const float* __restrict__ x, const int* __restrict__ Lbuf,
    float* __restrict__ out, int getstd)
{
    const int blk = blockIdx.x;
    const int b = blk / R;
    const int r = blk - b * R;

    const int L   = Lbuf[b];
    const int m   = L / R;
    const int gap = L - m * R;
    const int gl  = (gap + 1) >> 1;   // ceil(gap/2) leading windows of size m+1
    const int mid = R - gap;          // middle windows of size m

    int start, cnt;
    if (r < gl) {
        start = r * (m + 1);
        cnt   = m + 1;
    } else if (r < gl + mid) {
        start = gl * (m + 1) + (r - gl) * m;
        cnt   = m;
    } else {
        start = gl * (m + 1) + mid * m + (r - (gl + mid)) * (m + 1);
        cnt   = m + 1;
    }

    const int t = threadIdx.x;  // 0..319
    const float4* __restrict__ xr =
        reinterpret_cast<const float4*>(x + ((size_t)b * S + (size_t)start) * D) + t;

    float s0 = 0.f, s1 = 0.f, s2 = 0.f, s3 = 0.f;
    float q0 = 0.f, q1 = 0.f, q2 = 0.f, q3 = 0.f;

    for (int i = 0; i < cnt; ++i) {
        float4 v = xr[(size_t)i * (D / 4)];
        s0 += v.x; q0 = fmaf(v.x, v.x, q0);
        s1 += v.y; q1 = fmaf(v.y, v.y, q1);
        s2 += v.z; q2 = fmaf(v.z, v.z, q2);
        s3 += v.w; q3 = fmaf(v.w, v.w, q3);
    }

    const float inv = 1.0f / (float)cnt;
    const float m0 = s0 * inv, m1 = s1 * inv, m2 = s2 * inv, m3 = s3 * inv;

    const size_t obase = ((size_t)b * R + r) * D;
    float4 mv; mv.x = m0; mv.y = m1; mv.z = m2; mv.w = m3;
    reinterpret_cast<float4*>(out + obase)[t] = mv;

    if (getstd) {
        float v0 = fmaxf(fmaf(-m0, m0, q0 * inv), 0.f);
        float v1 = fmaxf(fmaf(-m1, m1, q1 * inv), 0.f);
        float v2 = fmaxf(fmaf(-m2, m2, q2 * inv), 0.f);
        float v3 = fmaxf(fmaf(-m3, m3, q3 * inv), 0.f);
        float4 sv;
        sv.x = sqrtf(v0); sv.y = sqrtf(v1); sv.z = sqrtf(v2); sv.w = sqrtf(v3);
        reinterpret_cast<float4*>(out + (size_t)B * R * D + obase)[t] = sv;
    }
}

extern "C" void kernel_launch(void* const* d_in, const int* in_sizes, int n_in,
                              void* d_out, int out_size, void* d_ws, size_t ws_size,
                              hipStream_t stream)
{
    const float* x    = (const float*)d_in[0];
    const int*   mask = (const int*)d_in[1];
    float*       out  = (float*)d_out;
    int*         Lbuf = (int*)d_ws;   // 32 ints

    // getstd is fixed at 1 in the harness; infer from out_size to stay
    // deterministic without reading device memory on host.
    const int getstd = (out_size >= 2 * B * R * D) ? 1 : 0;

    compute_len_kernel<<<B, 256, 0, stream>>>(mask, Lbuf);
    window_stats_kernel<<<B * R, 320, 0, stream>>>(x, Lbuf, out, getstd);
}

// Round 2
// 50.331 us; speedup vs baseline: 1.1474x; 1.1474x over previous
//
#include <hip/hip_runtime.h>

#define B 32
#define S 2048
#define D 1280
#define R 50

// One block per (b, r) window. 320 threads; lane t owns float4 column t
// (D = 1280 = 320*4). Length L is recomputed per block from the 8 KB mask
// row (L2-resident) to avoid a separate kernel + dependency. Single pass:
// sum + sum-of-squares, unrolled x4 for load pipelining.
__global__ __launch_bounds__(320) void window_stats_fused(
    const float* __restrict__ x, const int* __restrict__ mask,
    float* __restrict__ out, int getstd)
{
    const int blk = blockIdx.x;
    const int b = blk / R;
    const int r = blk - b * R;
    const int t = threadIdx.x;  // 0..319

    // ---- L = sum(mask[b,:]) ----
    const int4* __restrict__ mrow = reinterpret_cast<const int4*>(mask + (size_t)b * S);
    int lsum;
    {
        int4 v0 = mrow[t];                       // t < 512 (= S/4) always
        lsum = v0.x + v0.y + v0.z + v0.w;
        if (t + 320 < S / 4) {
            int4 v1 = mrow[t + 320];
            lsum += v1.x + v1.y + v1.z + v1.w;
        }
    }
    #pragma unroll
    for (int off = 32; off > 0; off >>= 1) lsum += __shfl_down(lsum, off, 64);
    __shared__ int wsum[5];
    if ((t & 63) == 0) wsum[t >> 6] = lsum;
    __syncthreads();
    const int L = wsum[0] + wsum[1] + wsum[2] + wsum[3] + wsum[4];

    // ---- window geometry (matches reference exactly) ----
    const int m   = L / R;
    const int gap = L - m * R;
    const int gl  = (gap + 1) >> 1;   // ceil(gap/2) leading windows of size m+1
    const int mid = R - gap;          // middle windows of size m

    int start, cnt;
    if (r < gl) {
        start = r * (m + 1);
        cnt   = m + 1;
    } else if (r < gl + mid) {
        start = gl * (m + 1) + (r - gl) * m;
        cnt   = m;
    } else {
        start = gl * (m + 1) + mid * m + (r - (gl + mid)) * (m + 1);
        cnt   = m + 1;
    }

    const float4* __restrict__ xr =
        reinterpret_cast<const float4*>(x + ((size_t)b * S + (size_t)start) * D) + t;

    // Two independent accumulator chains (A: slots 0,2; B: slots 1,3).
    float sA0 = 0.f, sA1 = 0.f, sA2 = 0.f, sA3 = 0.f;
    float qA0 = 0.f, qA1 = 0.f, qA2 = 0.f, qA3 = 0.f;
    float sB0 = 0.f, sB1 = 0.f, sB2 = 0.f, sB3 = 0.f;
    float qB0 = 0.f, qB1 = 0.f, qB2 = 0.f, qB3 = 0.f;

    int i = 0;
    for (; i + 4 <= cnt; i += 4) {
        float4 a = xr[(size_t)(i + 0) * (D / 4)];
        float4 c = xr[(size_t)(i + 1) * (D / 4)];
        float4 d = xr[(size_t)(i + 2) * (D / 4)];
        float4 e = xr[(size_t)(i + 3) * (D / 4)];

        sA0 += a.x; qA0 = fmaf(a.x, a.x, qA0);
        sA1 += a.y; qA1 = fmaf(a.y, a.y, qA1);
        sA2 += a.z; qA2 = fmaf(a.z, a.z, qA2);
        sA3 += a.w; qA3 = fmaf(a.w, a.w, qA3);

        sB0 += c.x; qB0 = fmaf(c.x, c.x, qB0);
        sB1 += c.y; qB1 = fmaf(c.y, c.y, qB1);
        sB2 += c.z; qB2 = fmaf(c.z, c.z, qB2);
        sB3 += c.w; qB3 = fmaf(c.w, c.w, qB3);

        sA0 += d.x; qA0 = fmaf(d.x, d.x, qA0);
        sA1 += d.y; qA1 = fmaf(d.y, d.y, qA1);
        sA2 += d.z; qA2 = fmaf(d.z, d.z, qA2);
        sA3 += d.w; qA3 = fmaf(d.w, d.w, qA3);

        sB0 += e.x; qB0 = fmaf(e.x, e.x, qB0);
        sB1 += e.y; qB1 = fmaf(e.y, e.y, qB1);
        sB2 += e.z; qB2 = fmaf(e.z, e.z, qB2);
        sB3 += e.w; qB3 = fmaf(e.w, e.w, qB3);
    }
    for (; i < cnt; ++i) {
        float4 a = xr[(size_t)i * (D / 4)];
        sA0 += a.x; qA0 = fmaf(a.x, a.x, qA0);
        sA1 += a.y; qA1 = fmaf(a.y, a.y, qA1);
        sA2 += a.z; qA2 = fmaf(a.z, a.z, qA2);
        sA3 += a.w; qA3 = fmaf(a.w, a.w, qA3);
    }

    const float s0 = sA0 + sB0, s1 = sA1 + sB1, s2 = sA2 + sB2, s3 = sA3 + sB3;
    const float q0 = qA0 + qB0, q1 = qA1 + qB1, q2 = qA2 + qB2, q3 = qA3 + qB3;

    const float inv = 1.0f / (float)cnt;
    const float m0 = s0 * inv, m1 = s1 * inv, m2 = s2 * inv, m3 = s3 * inv;

    const size_t obase = ((size_t)b * R + r) * D;
    float4 mv; mv.x = m0; mv.y = m1; mv.z = m2; mv.w = m3;
    reinterpret_cast<float4*>(out + obase)[t] = mv;

    if (getstd) {
        float v0 = fmaxf(fmaf(-m0, m0, q0 * inv), 0.f);
        float v1 = fmaxf(fmaf(-m1, m1, q1 * inv), 0.f);
        float v2 = fmaxf(fmaf(-m2, m2, q2 * inv), 0.f);
        float v3 = fmaxf(fmaf(-m3, m3, q3 * inv), 0.f);
        float4 sv;
        sv.x = sqrtf(v0); sv.y = sqrtf(v1); sv.z = sqrtf(v2); sv.w = sqrtf(v3);
        reinterpret_cast<float4*>(out + (size_t)B * R * D + obase)[t] = sv;
    }
}

extern "C" void kernel_launch(void* const* d_in, const int* in_sizes, int n_in,
                              void* d_out, int out_size, void* d_ws, size_t ws_size,
                              hipStream_t stream)
{
    const float* x    = (const float*)d_in[0];
    const int*   mask = (const int*)d_in[1];
    float*       out  = (float*)d_out;

    const int getstd = (out_size >= 2 * B * R * D) ? 1 : 0;

    window_stats_fused<<<B * R, 320, 0, stream>>>(x, mask, out, getstd);
}